// Round 1
// baseline (105.056 us; speedup 1.0000x reference)
//
#include <hip/hip_runtime.h>

#define NN 4096
#define BB 4
#define EE 256
#define DD 64
#define SCALE 0.125f

// Kernel 1: u[b,e] = sum_i val[b,i] * embed[pos[b,i], e];  V[b] = sum_i val[b,i]
// Grid: (NN/ROWS1, BB), block 256 (thread = embed column e).
#define ROWS1 32
__global__ void k_accum(const float* __restrict__ val, const int* __restrict__ pos,
                        const float* __restrict__ embed,
                        float* __restrict__ u, float* __restrict__ Vsum) {
    const int b = blockIdx.y;
    const int e = threadIdx.x;                 // 0..255
    const int base = blockIdx.x * ROWS1;
    float acc = 0.f;
    float vsum = 0.f;
    #pragma unroll 4
    for (int r = 0; r < ROWS1; ++r) {
        const int i = base + r;
        const float v = val[b * NN + i];       // block-uniform -> scalar load
        const int p = pos[b * NN + i];         // block-uniform -> scalar load
        acc += v * embed[(size_t)p * EE + e];  // coalesced 1KB/row across block
        vsum += v;
    }
    atomicAdd(&u[b * EE + e], acc);
    if (e == 0) atomicAdd(&Vsum[b], vsum);
}

// Kernel 2 (tiny): s[d] = bq[d]*V[b] + sum_e u[b,e]*Wq[d,e]
//                  w[b,e] = sum_d s[d]*Wk[d,e];  c[b] = sum_d s[d]*bk[d]
// Grid: BB blocks of 256.
__global__ void k_small(const float* __restrict__ u, const float* __restrict__ Vsum,
                        const float* __restrict__ Wq, const float* __restrict__ bq,
                        const float* __restrict__ Wk, const float* __restrict__ bk,
                        float* __restrict__ w, float* __restrict__ c) {
    const int b = blockIdx.x;
    const int t = threadIdx.x;
    __shared__ float sS[DD];
    if (t < DD) {
        float acc = bq[t] * Vsum[b];
        const float* uu = u + b * EE;
        const float* wq = Wq + t * EE;
        #pragma unroll 4
        for (int e = 0; e < EE; ++e) acc += uu[e] * wq[e];
        sS[t] = acc;
    }
    __syncthreads();
    float acc = 0.f;
    #pragma unroll 8
    for (int d = 0; d < DD; ++d) acc += sS[d] * Wk[d * EE + t];
    w[b * EE + t] = acc;
    if (t == 0) {
        float cc = 0.f;
        for (int d = 0; d < DD; ++d) cc += sS[d] * bk[d];
        c[b] = cc;
    }
}

// Kernel 3: out[b,j] = val[b,j] * (1 + SCALE*(embed[pos[b,j]]·w[b] + c[b]))
// One wave per row; lane loads float4 of the embed row; shfl reduce.
// Grid: (NN/(4*ROWS3), BB), block 256 = 4 waves.
#define ROWS3 4
__global__ void k_out(const float* __restrict__ val, const int* __restrict__ pos,
                      const float* __restrict__ embed,
                      const float* __restrict__ w, const float* __restrict__ c,
                      float* __restrict__ out) {
    const int b = blockIdx.y;
    const int lane = threadIdx.x & 63;
    const int wv = threadIdx.x >> 6;           // 0..3
    const int j0 = (blockIdx.x * 4 + wv) * ROWS3;
    const float4 wf = reinterpret_cast<const float4*>(w + b * EE)[lane];
    const float cb = c[b];
    #pragma unroll
    for (int r = 0; r < ROWS3; ++r) {
        const int j = j0 + r;
        const int p = pos[b * NN + j];
        const float4 ev = reinterpret_cast<const float4*>(embed + (size_t)p * EE)[lane];
        float acc = ev.x * wf.x + ev.y * wf.y + ev.z * wf.z + ev.w * wf.w;
        #pragma unroll
        for (int off = 32; off > 0; off >>= 1) acc += __shfl_down(acc, off, 64);
        if (lane == 0) {
            const float fx = SCALE * (acc + cb);
            const float v = val[b * NN + j];
            out[b * NN + j] = v * (1.f + fx);
        }
    }
}

extern "C" void kernel_launch(void* const* d_in, const int* in_sizes, int n_in,
                              void* d_out, int out_size, void* d_ws, size_t ws_size,
                              hipStream_t stream) {
    // inputs: t(0), val(1), pos(2), embed(3), Wq(4), bq(5), Wk(6), bk(7)
    const float* val   = (const float*)d_in[1];
    const int*   pos   = (const int*)d_in[2];
    const float* embed = (const float*)d_in[3];
    const float* Wq    = (const float*)d_in[4];
    const float* bq    = (const float*)d_in[5];
    const float* Wk    = (const float*)d_in[6];
    const float* bk    = (const float*)d_in[7];
    float* out = (float*)d_out;

    float* ws = (float*)d_ws;
    float* u  = ws;                       // BB*EE = 1024 floats
    float* V  = ws + BB * EE;             // BB floats
    float* w  = ws + BB * EE + BB;        // BB*EE floats
    float* c  = ws + 2 * BB * EE + BB;    // BB floats

    // zero the atomic accumulators (ws is poisoned 0xAA before every launch)
    hipMemsetAsync(u, 0, (BB * EE + BB) * sizeof(float), stream);

    dim3 g1(NN / ROWS1, BB);
    k_accum<<<g1, 256, 0, stream>>>(val, pos, embed, u, V);

    k_small<<<BB, 256, 0, stream>>>(u, V, Wq, bq, Wk, bk, w, c);

    dim3 g3(NN / (4 * ROWS3), BB);
    k_out<<<g3, 256, 0, stream>>>(val, pos, embed, w, c, out);
}

// Round 2
// 94.884 us; speedup vs baseline: 1.1072x; 1.1072x over previous
//
#include <hip/hip_runtime.h>

#define NN 4096
#define BB 4
#define EE 256
#define DD 64
#define SCALE 0.125f

// ---------------- Kernel 1 ----------------
// u[b,e] = sum_i val[b,i] * embed[pos[b,i], e];  V[b] = sum_i val[b,i]
// Block = 256 threads = 4 waves; each wave processes RW1 consecutive rows,
// lane l holds float4 of columns e = 4l..4l+3. Block-level LDS reduce, then
// one atomicAdd per (block, e).
#define RW1 16
#define RB1 (4 * RW1)   // 64 rows per block
__global__ __launch_bounds__(256) void k_accum(
        const float* __restrict__ val, const int* __restrict__ pos,
        const float* __restrict__ embed,
        float* __restrict__ u, float* __restrict__ Vsum) {
    const int b    = blockIdx.y;
    const int t    = threadIdx.x;
    const int lane = t & 63;
    const int wv   = t >> 6;
    const int base = blockIdx.x * RB1 + wv * RW1;

    float4 acc = make_float4(0.f, 0.f, 0.f, 0.f);
    float vsum = 0.f;
    #pragma unroll 4
    for (int r = 0; r < RW1; ++r) {
        const int i = base + r;
        const float v = val[b * NN + i];                    // broadcast
        const int   p = pos[b * NN + i];                    // broadcast
        const float4 ev = reinterpret_cast<const float4*>(embed + (size_t)p * EE)[lane];
        acc.x += v * ev.x; acc.y += v * ev.y;
        acc.z += v * ev.z; acc.w += v * ev.w;
        vsum += v;
    }

    __shared__ float part[4][EE];
    __shared__ float vpart[4];
    *reinterpret_cast<float4*>(&part[wv][lane * 4]) = acc;
    if (lane == 0) vpart[wv] = vsum;
    __syncthreads();

    const float s = part[0][t] + part[1][t] + part[2][t] + part[3][t];
    atomicAdd(&u[b * EE + t], s);
    if (t == 0) atomicAdd(&Vsum[b], vpart[0] + vpart[1] + vpart[2] + vpart[3]);
}

// ---------------- Kernel 2 (fused small-matvec + output) ----------------
// Per block (redundantly, W reads are L2-hot):
//   s[d]  = bq[d]*V[b] + sum_e u[b,e]*Wq[d,e]
//   w[e]  = sum_d s[d]*Wk[d,e]
//   c     = sum_d s[d]*bk[d]
// Then: out[b,j] = val[b,j] * (1 + SCALE*(embed[pos[b,j]]·w + c))
#define RW2 16
#define RB2 (4 * RW2)   // 64 rows per block
__global__ __launch_bounds__(256) void k_fused(
        const float* __restrict__ val, const int* __restrict__ pos,
        const float* __restrict__ embed,
        const float* __restrict__ u, const float* __restrict__ Vsum,
        const float* __restrict__ Wq, const float* __restrict__ bq,
        const float* __restrict__ Wk, const float* __restrict__ bk,
        float* __restrict__ out) {
    const int b    = blockIdx.y;
    const int t    = threadIdx.x;
    const int lane = t & 63;
    const int wv   = t >> 6;

    __shared__ float ps[4][DD];
    __shared__ float sS[DD];
    __shared__ float wsh[EE];
    __shared__ float cSh;

    // Phase A: s[d] — thread (seg,d) sums a 64-wide e-segment with float4 loads
    {
        const int d = t & 63, seg = t >> 6;
        const float4* uu = reinterpret_cast<const float4*>(u + b * EE + seg * 64);
        const float4* wq = reinterpret_cast<const float4*>(Wq + (size_t)d * EE + seg * 64);
        float acc = 0.f;
        #pragma unroll
        for (int q = 0; q < 16; ++q) {
            const float4 a = uu[q], w4 = wq[q];
            acc += a.x * w4.x + a.y * w4.y + a.z * w4.z + a.w * w4.w;
        }
        ps[seg][d] = acc;
    }
    __syncthreads();
    if (t < DD) sS[t] = ps[0][t] + ps[1][t] + ps[2][t] + ps[3][t] + bq[t] * Vsum[b];
    __syncthreads();

    // c (wave 0) and w[e] (all threads) in parallel
    if (wv == 0) {
        float x = sS[lane] * bk[lane];
        #pragma unroll
        for (int off = 32; off > 0; off >>= 1) x += __shfl_down(x, off, 64);
        if (lane == 0) cSh = x;
    }
    {
        float acc = 0.f;
        #pragma unroll
        for (int d = 0; d < DD; ++d) acc += sS[d] * Wk[d * EE + t];  // coalesced in t
        wsh[t] = acc;
    }
    __syncthreads();

    // Phase C: per-row dot with w, wave shfl reduce
    const float4 wf = reinterpret_cast<const float4*>(wsh)[lane];
    const float  cb = cSh;
    const int j0 = blockIdx.x * RB2 + wv * RW2;
    #pragma unroll 4
    for (int r = 0; r < RW2; ++r) {
        const int j = j0 + r;
        const int p = pos[b * NN + j];
        const float4 ev = reinterpret_cast<const float4*>(embed + (size_t)p * EE)[lane];
        float acc = ev.x * wf.x + ev.y * wf.y + ev.z * wf.z + ev.w * wf.w;
        #pragma unroll
        for (int off = 32; off > 0; off >>= 1) acc += __shfl_down(acc, off, 64);
        if (lane == 0) {
            const float v = val[b * NN + j];
            out[b * NN + j] = v * (1.f + SCALE * (acc + cb));
        }
    }
}

extern "C" void kernel_launch(void* const* d_in, const int* in_sizes, int n_in,
                              void* d_out, int out_size, void* d_ws, size_t ws_size,
                              hipStream_t stream) {
    // inputs: t(0), val(1), pos(2), embed(3), Wq(4), bq(5), Wk(6), bk(7)
    const float* val   = (const float*)d_in[1];
    const int*   pos   = (const int*)d_in[2];
    const float* embed = (const float*)d_in[3];
    const float* Wq    = (const float*)d_in[4];
    const float* bq    = (const float*)d_in[5];
    const float* Wk    = (const float*)d_in[6];
    const float* bk    = (const float*)d_in[7];
    float* out = (float*)d_out;

    float* ws = (float*)d_ws;
    float* u  = ws;              // BB*EE floats
    float* V  = ws + BB * EE;    // BB floats

    // zero the atomic accumulators (ws is poisoned 0xAA before every launch)
    hipMemsetAsync(u, 0, (BB * EE + BB) * sizeof(float), stream);

    dim3 g1(NN / RB1, BB);       // 64 x 4 = 256 blocks
    k_accum<<<g1, 256, 0, stream>>>(val, pos, embed, u, V);

    dim3 g2(NN / RB2, BB);       // 64 x 4 = 256 blocks
    k_fused<<<g2, 256, 0, stream>>>(val, pos, embed, u, V, Wq, bq, Wk, bk, out);
}

// Round 4
// 91.562 us; speedup vs baseline: 1.1474x; 1.0363x over previous
//
#include <hip/hip_runtime.h>

#define NN 4096
#define BB 4
#define EE 256
#define DD 64
#define SCALE 0.125f
#define NBLK 128   // gridDim.x for both kernels
#define RB 32      // rows per block
#define RW 8       // rows per wave (fully unrolled -> 8 gathers in flight)

// ---------------- Kernel 1 ----------------
// partial[b,blk,e] = sum_{i in blk} val[b,i]*embed[pos[b,i],e]
// vpart[b,blk]     = sum_{i in blk} val[b,i]
// No atomics, no zero-init needed (every slot overwritten).
__global__ __launch_bounds__(256) void k_accum(
        const float* __restrict__ val, const int* __restrict__ pos,
        const float* __restrict__ embed,
        float* __restrict__ part, float* __restrict__ vpart) {
    const int b = blockIdx.y, t = threadIdx.x;
    const int lane = t & 63, wv = t >> 6;
    const int base = b * NN + blockIdx.x * RB + wv * RW;

    float v[RW]; int p[RW];
    #pragma unroll
    for (int r = 0; r < RW; ++r) { v[r] = val[base + r]; p[r] = pos[base + r]; }

    float4 acc = make_float4(0.f, 0.f, 0.f, 0.f);
    float vs = 0.f;
    #pragma unroll
    for (int r = 0; r < RW; ++r) {
        const float4 ev = reinterpret_cast<const float4*>(embed + (size_t)p[r] * EE)[lane];
        acc.x += v[r] * ev.x; acc.y += v[r] * ev.y;
        acc.z += v[r] * ev.z; acc.w += v[r] * ev.w;
        vs += v[r];
    }

    __shared__ float plds[4][EE];
    __shared__ float vlds[4];
    *reinterpret_cast<float4*>(&plds[wv][4 * lane]) = acc;
    if (lane == 0) vlds[wv] = vs;
    __syncthreads();

    const float s = plds[0][t] + plds[1][t] + plds[2][t] + plds[3][t];
    part[((size_t)b * NBLK + blockIdx.x) * EE + t] = s;           // coalesced 1KB
    if (t == 0) vpart[b * NBLK + blockIdx.x] = vlds[0] + vlds[1] + vlds[2] + vlds[3];
}

// ---------------- Kernel 2 ----------------
// A0: u[e] = sum_blk part[b,blk,e];  V = sum_blk vpart[b,blk]
// A:  s[d] = bq[d]*V + sum_e u[e]*Wq[d,e]      (redundant per block; L2-hot)
// B:  w[e] = sum_d s[d]*Wk[d,e];  c = s.bk
// C:  out[b,j] = val[b,j]*(1 + SCALE*(embed[pos[b,j]].w + c))
__global__ __launch_bounds__(256) void k_fused(
        const float* __restrict__ val, const int* __restrict__ pos,
        const float* __restrict__ embed,
        const float* __restrict__ part, const float* __restrict__ vpart,
        const float* __restrict__ Wq, const float* __restrict__ bq,
        const float* __restrict__ Wk, const float* __restrict__ bk,
        float* __restrict__ out) {
    const int b = blockIdx.y, t = threadIdx.x;
    const int lane = t & 63, wv = t >> 6;

    __shared__ float uS[EE];
    __shared__ float ps[4][DD];
    __shared__ float sS[DD];
    __shared__ float wsh[EE];
    __shared__ float rowres[RB];
    __shared__ float cSh, vS;

    // ---- A0: reduce partials (coalesced, L2-hot, 128 independent loads) ----
    {
        float a = 0.f;
        const float* pp = part + (size_t)b * NBLK * EE + t;
        #pragma unroll 8
        for (int blk = 0; blk < NBLK; ++blk) a += pp[(size_t)blk * EE];
        uS[t] = a;
    }
    if (t < 64) {
        float x = vpart[b * NBLK + lane] + vpart[b * NBLK + 64 + lane];
        #pragma unroll
        for (int off = 32; off; off >>= 1) x += __shfl_down(x, off, 64);
        if (lane == 0) vS = x;
    }
    __syncthreads();

    // ---- A: s[d]; thread (seg=wv, d=lane) sums a 64-wide e-segment ----
    {
        const int d = lane, seg = wv;
        const float4* uu = reinterpret_cast<const float4*>(&uS[seg * 64]);
        const float4* wq = reinterpret_cast<const float4*>(Wq + (size_t)d * EE + seg * 64);
        float a = 0.f;
        #pragma unroll
        for (int q = 0; q < 16; ++q) {
            const float4 x = uu[q], y = wq[q];
            a += x.x * y.x + x.y * y.y + x.z * y.z + x.w * y.w;
        }
        ps[seg][d] = a;
    }
    __syncthreads();
    if (t < DD) sS[t] = ps[0][t] + ps[1][t] + ps[2][t] + ps[3][t] + bq[t] * vS;
    __syncthreads();

    // ---- B: c (wave 0) and w[e] (all threads) ----
    if (wv == 0) {
        float x = sS[lane] * bk[lane];
        #pragma unroll
        for (int off = 32; off; off >>= 1) x += __shfl_down(x, off, 64);
        if (lane == 0) cSh = x;
    }
    {
        float a = 0.f;
        #pragma unroll
        for (int d = 0; d < DD; ++d) a += sS[d] * Wk[d * EE + t];   // coalesced in t
        wsh[t] = a;
    }
    __syncthreads();

    // ---- C: 8 rows/wave, gathers fully unrolled, coalesced store via LDS ----
    const float4 wf = reinterpret_cast<const float4*>(wsh)[lane];
    const int base = b * NN + blockIdx.x * RB + wv * RW;
    int p[RW];
    #pragma unroll
    for (int r = 0; r < RW; ++r) p[r] = pos[base + r];
    #pragma unroll
    for (int r = 0; r < RW; ++r) {
        const float4 ev = reinterpret_cast<const float4*>(embed + (size_t)p[r] * EE)[lane];
        float a = ev.x * wf.x + ev.y * wf.y + ev.z * wf.z + ev.w * wf.w;
        #pragma unroll
        for (int off = 32; off; off >>= 1) a += __shfl_down(a, off, 64);
        if (lane == 0) rowres[wv * RW + r] = a;
    }
    __syncthreads();
    if (t < RB) {
        const int j = blockIdx.x * RB + t;
        const float v = val[b * NN + j];
        out[b * NN + j] = v * (1.f + SCALE * (rowres[t] + cSh));
    }
}

extern "C" void kernel_launch(void* const* d_in, const int* in_sizes, int n_in,
                              void* d_out, int out_size, void* d_ws, size_t ws_size,
                              hipStream_t stream) {
    // inputs: t(0), val(1), pos(2), embed(3), Wq(4), bq(5), Wk(6), bk(7)
    const float* val   = (const float*)d_in[1];
    const int*   pos   = (const int*)d_in[2];
    const float* embed = (const float*)d_in[3];
    const float* Wq    = (const float*)d_in[4];
    const float* bq    = (const float*)d_in[5];
    const float* Wk    = (const float*)d_in[6];
    const float* bk    = (const float*)d_in[7];
    float* out = (float*)d_out;

    float* part  = (float*)d_ws;                       // BB*NBLK*EE floats (512 KB)
    float* vpart = part + (size_t)BB * NBLK * EE;      // BB*NBLK floats

    dim3 g(NBLK, BB);   // 512 blocks each
    k_accum<<<g, 256, 0, stream>>>(val, pos, embed, part, vpart);
    k_fused<<<g, 256, 0, stream>>>(val, pos, embed, part, vpart, Wq, bq, Wk, bk, out);
}